// Round 1
// baseline (13677.902 us; speedup 1.0000x reference)
//
#include <hip/hip_runtime.h>

#define B_ 128
#define T_ 80
#define AD 32
#define ZD 64
#define KD 16
#define SZ 65   // stride (floats) for 64-col LDS matrices
#define SA 33   // stride (floats) for 32-col LDS matrices

// D[r2..r2+1][c4..c4+3] accumulate of P @ Q.
// ATRANS=false: A-operand element A[r][k] = Pa[r*AS + k]
// ATRANS=true : A-operand element A^T -> Pa[k*AS + r]
template<int KL, int AS, int BS, bool ATRANS>
__device__ __forceinline__ void mmacc(const float* __restrict__ Pa, const float* __restrict__ Qb,
                                      float acc[2][4], int r2, int c4)
{
    const float* pb = Qb + c4;
#pragma unroll 8
    for (int k = 0; k < KL; k++) {
        float aA, aB;
        if (ATRANS) { aA = Pa[k * AS + r2];       aB = Pa[k * AS + r2 + 1]; }
        else        { aA = Pa[r2 * AS + k];       aB = Pa[(r2 + 1) * AS + k]; }
        float b0 = pb[0], b1 = pb[1], b2 = pb[2], b3 = pb[3];
        acc[0][0] += aA * b0; acc[0][1] += aA * b1; acc[0][2] += aA * b2; acc[0][3] += aA * b3;
        acc[1][0] += aB * b0; acc[1][1] += aB * b1; acc[1][2] += aB * b2; acc[1][3] += aB * b3;
        pb += BS;
    }
}

__global__ __launch_bounds__(512)
void kvae_kernel(const float* __restrict__ obs, const float* __restrict__ logits,
                 const float* __restrict__ AK, const float* __restrict__ CK,
                 float* __restrict__ out)
{
    // ---- LDS pool (floats): 39232 * 4 = 156928 B  (<= 160 KiB/CU)
    __shared__ float lds[39232];
    float* W   = lds;            // [80][16]            1280
    float* Am  = lds + 1280;     // [64][65] A(t+1)     4160
    float* At  = Am + 4160;      // [64][65] A(t+1)^T   4160
    float* SP  = At + 4160;      // [64][65] sig_p      4160
    float* SF  = SP + 4160;      // [64][65] sig_f      4160
    float* Mm  = SF + 4160;      // [64][65] M / V      4160
    float* Rg  = Mm + 4160;      // region              16640
    float* VEC = Rg + 16640;     // vectors             512
    // forward aliases inside Rg
    float* T1 = Rg;              // [32][65] C@sig_p
    float* CM = Rg + 2080;       // [32][65] C
    float* CT = Rg + 4160;      // [64][33] C^T
    float* SS = Rg + 6272;      // [32][33] S -> chol L
    float* TI = Rg + 7328;      // [32][33] L^-1
    float* SI = Rg + 8384;      // [32][33] S^-1
    float* KG = Rg + 9440;      // [64][33] Kalman gain
    // backward aliases inside Rg
    float* LB = Rg;              // [64][65] chol L, later SPN^-1
    float* T6 = Rg + 4160;       // [64][65] L^-1 (64)
    float* X_ = Rg + 8320;       // [64][65] X = J^T
    float* SG = Rg + 12480;      // [64][65] sig_sm carry
    // vectors
    float* y   = VEC;            // 32
    float* mup = VEC + 32;       // 64 : Amu carry (A_{t+1} mu_f)
    float* err = VEC + 96;       // 32
    float* muf = VEC + 128;      // 64
    float* mus = VEC + 192;      // 64
    float* mpn = VEC + 256;      // 64
    float* dv  = VEC + 320;      // 64

    const int tid  = threadIdx.x;
    const int b    = blockIdx.x;
    const int lane = tid & 63;

    const int r16 = tid >> 4;        // 0..31
    const int cg  = tid & 15;        // 0..15
    const int c4  = cg << 2;         // 0..60 step 4
    const int c2  = cg << 1;         // 0..30 step 2
    const int r2  = r16 << 1;        // 0..62 step 2

    const float* obs_b = obs    + (size_t)b * T_ * AD;
    const float* lg_b  = logits + (size_t)b * T_ * KD;
    float* omu = out + (size_t)b * T_ * ZD;
    float* osg = out + (size_t)B_ * T_ * ZD + (size_t)b * T_ * ZD * ZD;

    // ---- prologue: softmax weights for all t; sig_p = 20 I; mup = 0
    if (tid < T_) {
        float l[KD]; float mx = -1e30f;
#pragma unroll
        for (int k = 0; k < KD; k++) { l[k] = lg_b[tid * KD + k]; mx = fmaxf(mx, l[k]); }
        float s = 0.f;
#pragma unroll
        for (int k = 0; k < KD; k++) { l[k] = expf(l[k] - mx); s += l[k]; }
        float inv = 1.0f / s;
#pragma unroll
        for (int k = 0; k < KD; k++) W[tid * KD + k] = l[k] * inv;
    }
#pragma unroll
    for (int rr = 0; rr < 2; rr++) {
        int r = r2 + rr;
#pragma unroll
        for (int j = 0; j < 4; j++) SP[r * SZ + c4 + j] = (r == c4 + j) ? 20.0f : 0.0f;
    }
    if (tid < ZD) mup[tid] = 0.0f;
    __syncthreads();

    // ---- mixing helpers
    auto mixA = [&](int tt) {
        const float4* AK4 = (const float4*)AK;
#pragma unroll
        for (int rr = 0; rr < 2; rr++) {
            int r = r2 + rr;
            float a0 = 0, a1 = 0, a2 = 0, a3 = 0;
#pragma unroll
            for (int k = 0; k < KD; k++) {
                float wk = W[tt * KD + k];
                float4 v = AK4[k * 1024 + r * 16 + cg];
                a0 += wk * v.x; a1 += wk * v.y; a2 += wk * v.z; a3 += wk * v.w;
            }
            Am[r * SZ + c4 + 0] = a0; Am[r * SZ + c4 + 1] = a1;
            Am[r * SZ + c4 + 2] = a2; Am[r * SZ + c4 + 3] = a3;
            At[(c4 + 0) * SZ + r] = a0; At[(c4 + 1) * SZ + r] = a1;
            At[(c4 + 2) * SZ + r] = a2; At[(c4 + 3) * SZ + r] = a3;
        }
    };
    auto mixC = [&](int tt) {
        const float4* CK4 = (const float4*)CK;
        int r = r16;
        float a0 = 0, a1 = 0, a2 = 0, a3 = 0;
#pragma unroll
        for (int k = 0; k < KD; k++) {
            float wk = W[tt * KD + k];
            float4 v = CK4[k * 512 + r * 16 + cg];
            a0 += wk * v.x; a1 += wk * v.y; a2 += wk * v.z; a3 += wk * v.w;
        }
        CM[r * SZ + c4 + 0] = a0; CM[r * SZ + c4 + 1] = a1;
        CM[r * SZ + c4 + 2] = a2; CM[r * SZ + c4 + 3] = a3;
        CT[(c4 + 0) * SA + r] = a0; CT[(c4 + 1) * SA + r] = a1;
        CT[(c4 + 2) * SA + r] = a2; CT[(c4 + 3) * SA + r] = a3;
    };

    // ================= FORWARD FILTER =================
    for (int t = 0; t < T_; t++) {
        // stage0: mix A(t+1) (if needed), C(t); load y
        if (t < T_ - 1) mixA(t + 1);
        mixC(t);
        if (tid < AD) y[tid] = obs_b[t * AD + tid];
        __syncthreads();

        // stage1: T1 = C @ sig_p   [32 x 64], k=64
        {
            float a0 = 0, a1 = 0, a2 = 0, a3 = 0;
            const float* pa = CM + r16 * SZ;
            const float* pb = SP + c4;
#pragma unroll 8
            for (int k = 0; k < ZD; k++) {
                float a = pa[k];
                a0 += a * pb[0]; a1 += a * pb[1]; a2 += a * pb[2]; a3 += a * pb[3];
                pb += SZ;
            }
            T1[r16 * SZ + c4 + 0] = a0; T1[r16 * SZ + c4 + 1] = a1;
            T1[r16 * SZ + c4 + 2] = a2; T1[r16 * SZ + c4 + 3] = a3;
        }
        __syncthreads();

        // stage2: S = T1 @ C^T + R   [32 x 32], k=64 ; err = y - C @ mup
        {
            float a0 = 0, a1 = 0;
            const float* pa = T1 + r16 * SZ;
            const float* pb = CT + c2;
#pragma unroll 8
            for (int k = 0; k < ZD; k++) {
                float a = pa[k];
                a0 += a * pb[0]; a1 += a * pb[1];
                pb += SA;
            }
            if (r16 == c2)     a0 += 0.03f;
            if (r16 == c2 + 1) a1 += 0.03f;
            SS[r16 * SA + c2] = a0; SS[r16 * SA + c2 + 1] = a1;
        }
        if (tid < AD) {
            float s = 0.f;
            const float* pc = CM + tid * SZ;
#pragma unroll 8
            for (int k = 0; k < ZD; k++) s += pc[k] * mup[k];
            err[tid] = y[tid] - s;
        }
        __syncthreads();

        // stage3: wave0: chol32(S)->SS(L), trinv32 -> TI
        if (tid < 64) {
            const int lr = lane & 31;
            float rr_[32];
#pragma unroll
            for (int k = 0; k < 32; k++) rr_[k] = SS[lr * SA + k];
#pragma unroll
            for (int j = 0; j < 32; j++) {
                float djj = __shfl(rr_[j], j);
                float di = rsqrtf(djj);
                di = di * (1.5f - 0.5f * djj * di * di);
                float l = rr_[j] * di;
                if (lane < 32) SS[lr * SA + j] = l;
#pragma unroll
                for (int k2 = j + 1; k2 < 32; k2++) rr_[k2] -= l * __shfl(l, k2);
            }
            // trinv: lane j owns column j of T = L^-1
            float tc[32];
#pragma unroll
            for (int i = 0; i < 32; i++) tc[i] = 0.f;
#pragma unroll
            for (int i = 0; i < 32; i++) {
                float Lii = SS[i * SA + i];
                float inv = 1.0f / Lii;
                float sA = 0, sB = 0, sC = 0, sD = 0;
                int k = 0;
#pragma unroll
                for (; k + 4 <= i; k += 4) {
                    sA += SS[i * SA + k] * tc[k];     sB += SS[i * SA + k + 1] * tc[k + 1];
                    sC += SS[i * SA + k + 2] * tc[k + 2]; sD += SS[i * SA + k + 3] * tc[k + 3];
                }
#pragma unroll
                for (; k < i; k++) sA += SS[i * SA + k] * tc[k];
                float s2 = (sA + sB) + (sC + sD);
                tc[i] = inv * ((lr == i) ? 1.0f : -s2);
                if (lane < 32) TI[i * SA + lr] = tc[i];
            }
        }
        __syncthreads();

        // stage4: S^-1 = TI^T @ TI   [32 x 32], k=32
        {
            float a0 = 0, a1 = 0;
            const float* pa = TI + r16;
            const float* pb = TI + c2;
#pragma unroll 8
            for (int k = 0; k < 32; k++) {
                float a = pa[k * SA];
                a0 += a * pb[0]; a1 += a * pb[1];
                pb += SA;
            }
            SI[r16 * SA + c2] = a0; SI[r16 * SA + c2 + 1] = a1;
        }
        __syncthreads();

        // stage5: Kg = T1^T @ S^-1   [64 x 32], k=32
        {
            float a00 = 0, a01 = 0, a10 = 0, a11 = 0;
            const float* pa = T1 + r2;
            const float* pb = SI + c2;
#pragma unroll 8
            for (int k = 0; k < 32; k++) {
                float aA = pa[k * SZ], aB = pa[k * SZ + 1];
                float b0 = pb[0], b1 = pb[1];
                a00 += aA * b0; a01 += aA * b1; a10 += aB * b0; a11 += aB * b1;
                pb += SA;
            }
            KG[r2 * SA + c2] = a00;       KG[r2 * SA + c2 + 1] = a01;
            KG[(r2 + 1) * SA + c2] = a10; KG[(r2 + 1) * SA + c2 + 1] = a11;
        }
        __syncthreads();

        // stage6: sig_f = sig_p - Kg @ T1 ; write out ; mu_f = mup + Kg @ err ; write out
        {
            float acc[2][4] = {};
            mmacc<AD, SA, SZ, false>(KG, T1, acc, r2, c4);
            float* og = osg + (size_t)t * ZD * ZD;
#pragma unroll
            for (int rr = 0; rr < 2; rr++) {
                int r = r2 + rr;
                float4 v;
                v.x = SP[r * SZ + c4 + 0] - acc[rr][0];
                v.y = SP[r * SZ + c4 + 1] - acc[rr][1];
                v.z = SP[r * SZ + c4 + 2] - acc[rr][2];
                v.w = SP[r * SZ + c4 + 3] - acc[rr][3];
                SF[r * SZ + c4 + 0] = v.x; SF[r * SZ + c4 + 1] = v.y;
                SF[r * SZ + c4 + 2] = v.z; SF[r * SZ + c4 + 3] = v.w;
                *(float4*)(og + r * ZD + c4) = v;
            }
        }
        if (tid < ZD) {
            float s = 0.f;
            const float* pk = KG + tid * SA;
#pragma unroll
            for (int k = 0; k < AD; k++) s += pk[k] * err[k];
            float v = mup[tid] + s;
            muf[tid] = v;
            omu[t * ZD + tid] = v;
        }
        __syncthreads();

        if (t < T_ - 1) {
            // stage7: M = A(t+1) @ sig_f   k=64
            {
                float acc[2][4] = {};
                mmacc<ZD, SZ, SZ, false>(Am, SF, acc, r2, c4);
#pragma unroll
                for (int rr = 0; rr < 2; rr++) {
                    int r = r2 + rr;
                    Mm[r * SZ + c4 + 0] = acc[rr][0]; Mm[r * SZ + c4 + 1] = acc[rr][1];
                    Mm[r * SZ + c4 + 2] = acc[rr][2]; Mm[r * SZ + c4 + 3] = acc[rr][3];
                }
            }
            __syncthreads();
            // stage8: sig_p' = M @ A^T + Q ; mup' = A(t+1) @ mu_f
            {
                float acc[2][4] = {};
                mmacc<ZD, SZ, SZ, false>(Mm, At, acc, r2, c4);
#pragma unroll
                for (int rr = 0; rr < 2; rr++) {
                    int r = r2 + rr;
#pragma unroll
                    for (int j = 0; j < 4; j++)
                        SP[r * SZ + c4 + j] = acc[rr][j] + ((r == c4 + j) ? 0.08f : 0.0f);
                }
            }
            if (tid < ZD) {
                float s = 0.f;
                const float* pa = Am + tid * SZ;
#pragma unroll 8
                for (int k = 0; k < ZD; k++) s += pa[k] * muf[k];
                mup[tid] = s;
            }
            __syncthreads();
        }
    }

    // ================= SMOOTHER INIT =================
#pragma unroll
    for (int rr = 0; rr < 2; rr++) {
        int r = r2 + rr;
#pragma unroll
        for (int j = 0; j < 4; j++) SG[r * SZ + c4 + j] = SF[r * SZ + c4 + j];
    }
    if (tid < ZD) mus[tid] = muf[tid];
    __syncthreads();

    // ================= BACKWARD SMOOTHER =================
    for (int t = T_ - 2; t >= 0; t--) {
        // stage0: mix A(t+1); load sig_f(t), mu_f(t) from out
        mixA(t + 1);
        {
            const float4* og4 = (const float4*)(osg + (size_t)t * ZD * ZD);
#pragma unroll
            for (int rr = 0; rr < 2; rr++) {
                int r = r2 + rr;
                float4 v = og4[r * 16 + cg];
                SF[r * SZ + c4 + 0] = v.x; SF[r * SZ + c4 + 1] = v.y;
                SF[r * SZ + c4 + 2] = v.z; SF[r * SZ + c4 + 3] = v.w;
            }
        }
        if (tid < ZD) muf[tid] = omu[t * ZD + tid];
        __syncthreads();

        // stage1: M = A(t+1) @ sig_f
        {
            float acc[2][4] = {};
            mmacc<ZD, SZ, SZ, false>(Am, SF, acc, r2, c4);
#pragma unroll
            for (int rr = 0; rr < 2; rr++) {
                int r = r2 + rr;
                Mm[r * SZ + c4 + 0] = acc[rr][0]; Mm[r * SZ + c4 + 1] = acc[rr][1];
                Mm[r * SZ + c4 + 2] = acc[rr][2]; Mm[r * SZ + c4 + 3] = acc[rr][3];
            }
        }
        __syncthreads();

        // stage2: spn = M @ A^T + Q (-> SP) ; mpn = A(t+1) @ mu_f
        {
            float acc[2][4] = {};
            mmacc<ZD, SZ, SZ, false>(Mm, At, acc, r2, c4);
#pragma unroll
            for (int rr = 0; rr < 2; rr++) {
                int r = r2 + rr;
#pragma unroll
                for (int j = 0; j < 4; j++)
                    SP[r * SZ + c4 + j] = acc[rr][j] + ((r == c4 + j) ? 0.08f : 0.0f);
            }
        }
        if (tid < ZD) {
            float s = 0.f;
            const float* pa = Am + tid * SZ;
#pragma unroll 8
            for (int k = 0; k < ZD; k++) s += pa[k] * muf[k];
            mpn[tid] = s;
        }
        __syncthreads();

        // stage3: wave0: chol64(spn) -> LB ; trinv64 -> T6 ;  wave1: dv = mus - mpn
        if (tid >= 64 && tid < 128) { int i = tid - 64; dv[i] = mus[i] - mpn[i]; }
        if (tid < 64) {
            float rr_[64];
#pragma unroll
            for (int k = 0; k < 64; k++) rr_[k] = SP[lane * SZ + k];
#pragma unroll
            for (int j = 0; j < 64; j++) {
                float djj = __shfl(rr_[j], j);
                float di = rsqrtf(djj);
                di = di * (1.5f - 0.5f * djj * di * di);
                float l = rr_[j] * di;
                LB[lane * SZ + j] = l;
#pragma unroll
                for (int k2 = j + 1; k2 < 64; k2++) rr_[k2] -= l * __shfl(l, k2);
            }
            float tc[64];
#pragma unroll
            for (int i = 0; i < 64; i++) tc[i] = 0.f;
#pragma unroll
            for (int i = 0; i < 64; i++) {
                float Lii = LB[i * SZ + i];
                float inv = 1.0f / Lii;
                float sA = 0, sB = 0, sC = 0, sD = 0;
                int k = 0;
#pragma unroll
                for (; k + 4 <= i; k += 4) {
                    sA += LB[i * SZ + k] * tc[k];         sB += LB[i * SZ + k + 1] * tc[k + 1];
                    sC += LB[i * SZ + k + 2] * tc[k + 2]; sD += LB[i * SZ + k + 3] * tc[k + 3];
                }
#pragma unroll
                for (; k < i; k++) sA += LB[i * SZ + k] * tc[k];
                float s2 = (sA + sB) + (sC + sD);
                tc[i] = inv * ((lane == i) ? 1.0f : -s2);
                T6[i * SZ + lane] = tc[i];
            }
        }
        __syncthreads();

        // stage4: spn^-1 = T6^T @ T6  (-> LB)
        {
            float acc[2][4] = {};
            mmacc<ZD, SZ, SZ, true>(T6, T6, acc, r2, c4);
#pragma unroll
            for (int rr = 0; rr < 2; rr++) {
                int r = r2 + rr;
                LB[r * SZ + c4 + 0] = acc[rr][0]; LB[r * SZ + c4 + 1] = acc[rr][1];
                LB[r * SZ + c4 + 2] = acc[rr][2]; LB[r * SZ + c4 + 3] = acc[rr][3];
            }
        }
        __syncthreads();

        // stage5: X = spn^-1 @ M   (X = J^T)
        {
            float acc[2][4] = {};
            mmacc<ZD, SZ, SZ, false>(LB, Mm, acc, r2, c4);
#pragma unroll
            for (int rr = 0; rr < 2; rr++) {
                int r = r2 + rr;
                X_[r * SZ + c4 + 0] = acc[rr][0]; X_[r * SZ + c4 + 1] = acc[rr][1];
                X_[r * SZ + c4 + 2] = acc[rr][2]; X_[r * SZ + c4 + 3] = acc[rr][3];
            }
        }
        __syncthreads();

        // stage6: V = (sig_s - spn) @ X  (-> Mm)
        {
            float acc[2][4] = {};
            const float* ps0 = SG + r2 * SZ;       const float* pq0 = SP + r2 * SZ;
            const float* ps1 = SG + (r2 + 1) * SZ; const float* pq1 = SP + (r2 + 1) * SZ;
            const float* pb = X_ + c4;
#pragma unroll 8
            for (int k = 0; k < ZD; k++) {
                float aA = ps0[k] - pq0[k];
                float aB = ps1[k] - pq1[k];
                float b0 = pb[0], b1 = pb[1], b2 = pb[2], b3 = pb[3];
                acc[0][0] += aA * b0; acc[0][1] += aA * b1; acc[0][2] += aA * b2; acc[0][3] += aA * b3;
                acc[1][0] += aB * b0; acc[1][1] += aB * b1; acc[1][2] += aB * b2; acc[1][3] += aB * b3;
                pb += SZ;
            }
#pragma unroll
            for (int rr = 0; rr < 2; rr++) {
                int r = r2 + rr;
                Mm[r * SZ + c4 + 0] = acc[rr][0]; Mm[r * SZ + c4 + 1] = acc[rr][1];
                Mm[r * SZ + c4 + 2] = acc[rr][2]; Mm[r * SZ + c4 + 3] = acc[rr][3];
            }
        }
        __syncthreads();

        // stage7: sig_sm = sig_f + V^T @ X  (-> SG, out) ; mu_sm = mu_f + X^T dv (-> mus, out)
        {
            float acc[2][4] = {};
            mmacc<ZD, SZ, SZ, true>(Mm, X_, acc, r2, c4);
            float* og = osg + (size_t)t * ZD * ZD;
#pragma unroll
            for (int rr = 0; rr < 2; rr++) {
                int r = r2 + rr;
                float4 v;
                v.x = SF[r * SZ + c4 + 0] + acc[rr][0];
                v.y = SF[r * SZ + c4 + 1] + acc[rr][1];
                v.z = SF[r * SZ + c4 + 2] + acc[rr][2];
                v.w = SF[r * SZ + c4 + 3] + acc[rr][3];
                SG[r * SZ + c4 + 0] = v.x; SG[r * SZ + c4 + 1] = v.y;
                SG[r * SZ + c4 + 2] = v.z; SG[r * SZ + c4 + 3] = v.w;
                *(float4*)(og + r * ZD + c4) = v;
            }
        }
        if (tid < ZD) {
            float s = 0.f;
            const float* px = X_ + tid;
#pragma unroll 8
            for (int k = 0; k < ZD; k++) s += px[k * SZ] * dv[k];
            float v = muf[tid] + s;
            mus[tid] = v;
            omu[t * ZD + tid] = v;
        }
        __syncthreads();
    }
}

extern "C" void kernel_launch(void* const* d_in, const int* in_sizes, int n_in,
                              void* d_out, int out_size, void* d_ws, size_t ws_size,
                              hipStream_t stream) {
    const float* obs = (const float*)d_in[0];
    const float* lg  = (const float*)d_in[1];
    const float* AK  = (const float*)d_in[2];
    const float* CK  = (const float*)d_in[3];
    (void)d_ws; (void)ws_size; (void)in_sizes; (void)n_in; (void)out_size;
    kvae_kernel<<<dim3(B_), dim3(512), 0, stream>>>(obs, lg, AK, CK, (float*)d_out);
}